// Round 2
// baseline (309.107 us; speedup 1.0000x reference)
//
#include <hip/hip_runtime.h>
#include <hip/hip_bf16.h>

#define DIM 32

// ---------------------------------------------------------------------------
// Kernel 1: out = x @ W2^T + b2 ;  y = x @ W1^T
// Grid-stride over 8-row tiles; weights staged in LDS ONCE per block.
// ---------------------------------------------------------------------------
__global__ __launch_bounds__(256) void fused_lin_kernel(
    const float* __restrict__ x,
    const float* __restrict__ W1,
    const float* __restrict__ W2,
    const float* __restrict__ b2,
    float* __restrict__ out,
    float* __restrict__ y,
    int n_nodes)
{
    __shared__ float W1s[DIM][DIM];  // W1s[k][c] = W1[c][k]
    __shared__ float W2s[DIM][DIM];
    __shared__ float b2s[DIM];
    __shared__ float xs[8][DIM];

    const int t = threadIdx.x;
    for (int i = t; i < DIM * DIM; i += 256) {
        int c = i >> 5, k = i & 31;
        W1s[k][c] = W1[i];
        W2s[k][c] = W2[i];
    }
    if (t < DIM) b2s[t] = b2[t];

    const int r = t >> 5;   // 0..7
    const int c = t & 31;   // 0..31
    const int ntiles = (n_nodes + 7) >> 3;

    for (int tile = blockIdx.x; tile < ntiles; tile += gridDim.x) {
        const int row = tile * 8 + r;
        __syncthreads();   // also covers initial weight staging
        if (row < n_nodes) xs[r][c] = x[(long)row * DIM + c];
        __syncthreads();
        if (row < n_nodes) {
            float a2 = b2s[c];
            float a1 = 0.0f;
            #pragma unroll
            for (int k = 0; k < DIM; ++k) {
                float xv = xs[r][k];          // LDS broadcast
                a2 += xv * W2s[k][c];         // bank = c, conflict-free
                a1 += xv * W1s[k][c];
            }
            out[(long)row * DIM + c] = a2;
            y[(long)row * DIM + c]   = a1;
        }
    }
}

// ---------------------------------------------------------------------------
// CSR build: histogram -> 3-step exclusive scan -> slot-scatter
// ---------------------------------------------------------------------------
__global__ __launch_bounds__(256) void hist_kernel(
    const int* __restrict__ dst, int* __restrict__ counts, int nE)
{
    int i = blockIdx.x * 256 + threadIdx.x;
    if (i < nE) atomicAdd(&counts[dst[i]], 1);
}

__global__ __launch_bounds__(1024) void scan1_kernel(
    const int* __restrict__ counts, int* __restrict__ exscan,
    int* __restrict__ block_sums, int n)
{
    __shared__ int s[1024];
    const int t = threadIdx.x;
    const int i = blockIdx.x * 1024 + t;
    int v = (i < n) ? counts[i] : 0;
    s[t] = v;
    __syncthreads();
    for (int off = 1; off < 1024; off <<= 1) {
        int add = (t >= off) ? s[t - off] : 0;
        __syncthreads();
        s[t] += add;
        __syncthreads();
    }
    if (i < n) exscan[i] = s[t] - v;            // exclusive within block
    if (t == 1023) block_sums[blockIdx.x] = s[t];
}

__global__ __launch_bounds__(1024) void scan2_kernel(
    int* __restrict__ bs, int nb)   // nb <= 1024
{
    __shared__ int s[1024];
    const int t = threadIdx.x;
    int v = (t < nb) ? bs[t] : 0;
    s[t] = v;
    __syncthreads();
    for (int off = 1; off < 1024; off <<= 1) {
        int add = (t >= off) ? s[t - off] : 0;
        __syncthreads();
        s[t] += add;
        __syncthreads();
    }
    if (t < nb) bs[t] = s[t] - v;               // exclusive block offsets
}

__global__ __launch_bounds__(256) void scan3_kernel(
    const int* __restrict__ exscan, const int* __restrict__ block_sums,
    int* __restrict__ row_start, int* __restrict__ cursor, int n)
{
    int i = blockIdx.x * 256 + threadIdx.x;
    if (i < n) {
        int v = exscan[i] + block_sums[i >> 10];
        row_start[i] = v;
        cursor[i]    = v;
    }
}

__global__ __launch_bounds__(256) void build_csr_kernel(
    const int* __restrict__ src, const int* __restrict__ dst,
    int* __restrict__ cursor, int* __restrict__ csr_src, int nE)
{
    int e = blockIdx.x * 256 + threadIdx.x;
    if (e < nE) {
        int p = atomicAdd(&cursor[dst[e]], 1);
        csr_src[p] = src[e];
    }
}

// ---------------------------------------------------------------------------
// Gather: one wave per destination node. Lanes = (edge_parity, dim).
// out[i][:] += sum_{e in csr[i]} y[src_e][:]   (single writer, no atomics)
// ---------------------------------------------------------------------------
__global__ __launch_bounds__(256) void gather_kernel(
    const int* __restrict__ row_start, const int* __restrict__ counts,
    const int* __restrict__ csr_src, const float* __restrict__ y,
    float* __restrict__ out, int n_nodes)
{
    const int wid  = (blockIdx.x * 256 + threadIdx.x) >> 6;  // node id
    const int lane = threadIdx.x & 63;
    if (wid >= n_nodes) return;

    const int start = row_start[wid];
    const int end   = start + counts[wid];
    const int el = lane >> 5;   // 0 or 1: which edge of the pair
    const int d  = lane & 31;   // dim

    float acc = 0.0f;
    for (int e = start + el; e < end; e += 2) {
        int s = csr_src[e];                    // uniform across 32 lanes
        acc += y[(long)s * DIM + d];           // 128B coalesced row read
    }
    acc += __shfl_xor(acc, 32);                // combine the two edge lanes
    if (el == 0) out[(long)wid * DIM + d] += acc;
}

// ---------------------------------------------------------------------------
// Fallback (ws too small): direct atomic scatter (round-1 kernel)
// ---------------------------------------------------------------------------
__global__ __launch_bounds__(256) void edge_scatter_kernel(
    const int* __restrict__ src, const int* __restrict__ dst,
    const float* __restrict__ y, float* __restrict__ out, long total)
{
    long gid = (long)blockIdx.x * 256 + threadIdx.x;
    if (gid >= total) return;
    int e = (int)(gid >> 5);
    int d = (int)(gid & 31);
    atomicAdd(&out[(long)dst[e] * DIM + d], y[(long)src[e] * DIM + d]);
}

extern "C" void kernel_launch(void* const* d_in, const int* in_sizes, int n_in,
                              void* d_out, int out_size, void* d_ws, size_t ws_size,
                              hipStream_t stream) {
    const float* x  = (const float*)d_in[0];
    const float* W1 = (const float*)d_in[1];
    const float* W2 = (const float*)d_in[2];
    const float* b2 = (const float*)d_in[3];
    const int*   ei = (const int*)d_in[4];

    const int n_nodes = in_sizes[0] / DIM;   // 100000
    const int n_edges = in_sizes[4] / 2;     // 1,600,000
    const int* src = ei;
    const int* dst = ei + n_edges;
    float* out = (float*)d_out;

    // workspace layout (all 4-byte elements, 256B-aligned chunks)
    char* base = (char*)d_ws;
    size_t off = 0;
    auto alloc = [&](size_t bytes) {
        char* p = base + off;
        off = (off + bytes + 255) & ~(size_t)255;
        return p;
    };
    float* y          = (float*)alloc((size_t)n_nodes * DIM * sizeof(float));
    int*   counts     = (int*)  alloc((size_t)n_nodes * sizeof(int));
    int*   row_start  = (int*)  alloc((size_t)n_nodes * sizeof(int));
    int*   cursor     = (int*)  alloc((size_t)n_nodes * sizeof(int));
    int*   csr_src    = (int*)  alloc((size_t)n_edges * sizeof(int));
    int*   block_sums = (int*)  alloc(1024 * sizeof(int));
    const bool have_ws = off <= ws_size;

    // Kernel 1: the two linear maps (grid-stride, 1024 blocks)
    fused_lin_kernel<<<1024, 256, 0, stream>>>(x, W1, W2, b2, out, y, n_nodes);

    if (have_ws) {
        const int nb = (n_nodes + 1023) / 1024;   // 98 <= 1024
        hipMemsetAsync(counts, 0, (size_t)n_nodes * sizeof(int), stream);
        hist_kernel<<<(n_edges + 255) / 256, 256, 0, stream>>>(dst, counts, n_edges);
        scan1_kernel<<<nb, 1024, 0, stream>>>(counts, row_start /*tmp exscan*/, block_sums, n_nodes);
        scan2_kernel<<<1, 1024, 0, stream>>>(block_sums, nb);
        scan3_kernel<<<(n_nodes + 255) / 256, 256, 0, stream>>>(row_start, block_sums, row_start, cursor, n_nodes);
        build_csr_kernel<<<(n_edges + 255) / 256, 256, 0, stream>>>(src, dst, cursor, csr_src, n_edges);
        gather_kernel<<<(n_nodes * 64 + 255) / 256, 256, 0, stream>>>(row_start, counts, csr_src, y, out, n_nodes);
    } else {
        long total = (long)n_edges * DIM;
        edge_scatter_kernel<<<(int)((total + 255) / 256), 256, 0, stream>>>(src, dst, y, out, total);
    }
}